// Round 13
// baseline (601.180 us; speedup 1.0000x reference)
//
#include <hip/hip_runtime.h>

// GRU: B=256, T=1000, I=64, H=128 (3H=384).
// Round-13: scale-out step 3 on the r11 MFMA structure: 64 blocks x M=4
// batch rows (rows 4-15 of the MFMA tile zero-padded). Per-CU MFMA pipe
// time is invariant under this split (~570-700 cyc/step floor); the lever
// is per-lane gate work: 2 -> 1 gate-triple per lane (6 TRANS), 4-way
// C-redistribution via 12 bpermutes. MFMA/LDS layout byte-identical to
// r11/r12 (verified passing). Stores: 1 state + 1 hbuf write per lane.

#define Tc 1000
#define Ic 64
#define Hc 128
#define Bc 256
#define MBLK 4
#define NBLOCKS 64

typedef _Float16 half8 __attribute__((ext_vector_type(8)));
typedef float f32x4 __attribute__((ext_vector_type(4)));

#define MFMA_F16(A, B, C) __builtin_amdgcn_mfma_f32_16x16x32_f16((A), (B), (C), 0, 0, 0)

__device__ __forceinline__ float fast_sigmoid(float x) {
    return __builtin_amdgcn_rcpf(1.0f + __expf(-x));
}
__device__ __forceinline__ float fast_tanh(float x) {
    return 1.0f - 2.0f * __builtin_amdgcn_rcpf(__expf(2.0f * x) + 1.0f);
}

__global__ __launch_bounds__(512, 2) void gru_mfma_kernel(
    const float* __restrict__ input,   // [B][T][I]
    const float* __restrict__ W_ih,    // [3H][I]
    const float* __restrict__ W_hh,    // [3H][H]
    const float* __restrict__ b_ih,    // [3H]
    const float* __restrict__ b_hh,    // [3H]
    float* __restrict__ out)           // states [B][T][H] then hT [B][H]
{
    const int blk = blockIdx.x;
    const int tid = threadIdx.x;
    const int l   = tid & 63;
    const int w   = tid >> 6;    // wave 0..7
    const int ln  = l & 15;      // A-row m / B-col n offset
    const int lg  = l >> 4;      // k-group 0..3; also this lane's owned batch row
    const int j   = w * 16 + ln; // this lane's gate column / h-unit

    __shared__ __align__(16) _Float16 hbuf[2][16][136];  // h(t) f16; rows 4-15 stay 0
    __shared__ __align__(16) _Float16 xbuf[2][16][72];   // x rows f16; rows 4-15 stay 0

    // ---------- persistent B-fragments (identical to r11/r12, verified) ----------
    half8 bh[3][4], bx[3][2];
#pragma unroll
    for (int g = 0; g < 3; ++g) {
        const float* rw = W_hh + (size_t)(g * Hc + j) * Hc;
#pragma unroll
        for (int kc = 0; kc < 4; ++kc) {
            const float* p = rw + kc * 32 + lg * 8;
            half8 f;
#pragma unroll
            for (int e = 0; e < 8; ++e) f[e] = (_Float16)p[e];
            bh[g][kc] = f;
        }
        const float* rx = W_ih + (size_t)(g * Hc + j) * Ic;
#pragma unroll
        for (int kc = 0; kc < 2; ++kc) {
            const float* p = rx + kc * 32 + lg * 8;
            half8 f;
#pragma unroll
            for (int e = 0; e < 8; ++e) f[e] = (_Float16)p[e];
            bx[g][kc] = f;
        }
    }

    const float br0 = b_ih[j] + b_hh[j];
    const float bz0 = b_ih[Hc + j] + b_hh[Hc + j];
    const float bnx = b_ih[2 * Hc + j];
    const float bnh = b_hh[2 * Hc + j];

    // ---------- input staging geometry (4 real rows) ----------
    const int  sm  = tid >> 5;          // 0..15
    const int  sk  = (tid & 31) * 2;
    const bool stg = sm < MBLK;
    const float* inrow = input + (size_t)(blk * MBLK + (stg ? sm : 0)) * Tc * Ic + sk;

    // zero all of hbuf/xbuf (h(-1)=0; pad rows stay 0 forever)
    for (int i = tid; i < 2 * 16 * 136; i += 512) (&hbuf[0][0][0])[i] = (_Float16)0.0f;
    for (int i = tid; i < 2 * 16 * 72;  i += 512) (&xbuf[0][0][0])[i] = (_Float16)0.0f;
    __syncthreads();

    float2 xpre0 = {0.f, 0.f}, xpre1 = {0.f, 0.f};
    if (stg) {   // stage x rows 0,1; prefetch rows 2,3
        float2 v0 = *reinterpret_cast<const float2*>(inrow);
        float2 v1 = *reinterpret_cast<const float2*>(inrow + Ic);
        union { _Float16 h[2]; unsigned u; } p0, p1;
        p0.h[0] = (_Float16)v0.x; p0.h[1] = (_Float16)v0.y;
        p1.h[0] = (_Float16)v1.x; p1.h[1] = (_Float16)v1.y;
        *reinterpret_cast<unsigned*>(&xbuf[0][sm][sk]) = p0.u;
        *reinterpret_cast<unsigned*>(&xbuf[1][sm][sk]) = p1.u;
        xpre0 = *reinterpret_cast<const float2*>(inrow + 2 * Ic);
        xpre1 = *reinterpret_cast<const float2*>(inrow + 3 * Ic);
    }
    __syncthreads();

    // ---------- prologue: x-projection for t=0 ----------
    f32x4 cr  = {br0, br0, br0, br0};
    f32x4 cz  = {bz0, bz0, bz0, bz0};
    f32x4 cxn = {bnx, bnx, bnx, bnx};
    {
        const _Float16* xr = &xbuf[0][ln][lg * 8];
        half8 xa0 = *reinterpret_cast<const half8*>(xr);
        half8 xa1 = *reinterpret_cast<const half8*>(xr + 32);
        cr  = MFMA_F16(xa0, bx[0][0], cr);  cr  = MFMA_F16(xa1, bx[0][1], cr);
        cz  = MFMA_F16(xa0, bx[1][0], cz);  cz  = MFMA_F16(xa1, bx[1][1], cz);
        cxn = MFMA_F16(xa0, bx[2][0], cxn); cxn = MFMA_F16(xa1, bx[2][1], cxn);
    }
    float hold = 0.f;   // this lane's h (row lg, col j)

    float* sP  = out + (size_t)(blk * MBLK + lg) * Tc * Hc + j;   // states run-ptr
    float* hTp = out + (size_t)Bc * Tc * Hc + (size_t)(blk * MBLK + lg) * Hc + j;

#define GRU_STEP(T_, PAR_, XPRE_)                                               \
    {                                                                           \
        __syncthreads();                                                        \
        const _Float16* hrp = &hbuf[1 - (PAR_)][ln][lg * 8];                    \
        half8 ha0 = *reinterpret_cast<const half8*>(hrp);                       \
        half8 ha1 = *reinterpret_cast<const half8*>(hrp + 32);                  \
        half8 ha2 = *reinterpret_cast<const half8*>(hrp + 64);                  \
        half8 ha3 = *reinterpret_cast<const half8*>(hrp + 96);                  \
        f32x4 chn = {bnh, bnh, bnh, bnh};                                       \
        cr = MFMA_F16(ha0, bh[0][0], cr); cz = MFMA_F16(ha0, bh[1][0], cz);     \
        chn = MFMA_F16(ha0, bh[2][0], chn);                                     \
        cr = MFMA_F16(ha1, bh[0][1], cr); cz = MFMA_F16(ha1, bh[1][1], cz);     \
        chn = MFMA_F16(ha1, bh[2][1], chn);                                     \
        cr = MFMA_F16(ha2, bh[0][2], cr); cz = MFMA_F16(ha2, bh[1][2], cz);     \
        chn = MFMA_F16(ha2, bh[2][2], chn);                                     \
        cr = MFMA_F16(ha3, bh[0][3], cr); cz = MFMA_F16(ha3, bh[1][3], cz);     \
        chn = MFMA_F16(ha3, bh[2][3], chn);                                     \
        const _Float16* xrp = &xbuf[1 - (PAR_)][ln][lg * 8];                    \
        half8 xa0 = *reinterpret_cast<const half8*>(xrp);                       \
        half8 xa1 = *reinterpret_cast<const half8*>(xrp + 32);                  \
        f32x4 nr = {br0, br0, br0, br0};                                        \
        f32x4 nz = {bz0, bz0, bz0, bz0};                                        \
        f32x4 nx = {bnx, bnx, bnx, bnx};                                        \
        nr = MFMA_F16(xa0, bx[0][0], nr); nr = MFMA_F16(xa1, bx[0][1], nr);     \
        nz = MFMA_F16(xa0, bx[1][0], nz); nz = MFMA_F16(xa1, bx[1][1], nz);     \
        nx = MFMA_F16(xa0, bx[2][0], nx); nx = MFMA_F16(xa1, bx[2][1], nx);     \
        if (stg) {                                                              \
            union { _Float16 h[2]; unsigned u; } pk;                            \
            pk.h[0] = (_Float16)XPRE_.x; pk.h[1] = (_Float16)XPRE_.y;           \
            *reinterpret_cast<unsigned*>(&xbuf[PAR_][sm][sk]) = pk.u;           \
            const int trow = ((T_) + 4 < Tc) ? ((T_) + 4) : (Tc - 1);           \
            XPRE_ = *reinterpret_cast<const float2*>(inrow + (size_t)trow * Ic);\
        }                                                                       \
        /* 4-way redistribution: quarter q gets elem q from lane (l&15) */      \
        const float rA1 = __shfl(cr[1], ln),  rA2 = __shfl(cr[2], ln),          \
                    rA3 = __shfl(cr[3], ln);                                    \
        const float zA1 = __shfl(cz[1], ln),  zA2 = __shfl(cz[2], ln),          \
                    zA3 = __shfl(cz[3], ln);                                    \
        const float xA1 = __shfl(cxn[1], ln), xA2 = __shfl(cxn[2], ln),         \
                    xA3 = __shfl(cxn[3], ln);                                   \
        const float hA1 = __shfl(chn[1], ln), hA2 = __shfl(chn[2], ln),         \
                    hA3 = __shfl(chn[3], ln);                                   \
        const float aR = (lg == 0) ? cr[0]  : (lg == 1) ? rA1 : (lg == 2) ? rA2 : rA3; \
        const float aZ = (lg == 0) ? cz[0]  : (lg == 1) ? zA1 : (lg == 2) ? zA2 : zA3; \
        const float aX = (lg == 0) ? cxn[0] : (lg == 1) ? xA1 : (lg == 2) ? xA2 : xA3; \
        const float aH = (lg == 0) ? chn[0] : (lg == 1) ? hA1 : (lg == 2) ? hA2 : hA3; \
        const float rg = fast_sigmoid(aR), zg = fast_sigmoid(aZ);               \
        const float nv = fast_tanh(aX + rg * aH);                               \
        const float hN = nv + zg * (hold - nv);                                 \
        hbuf[PAR_][lg][j] = (_Float16)hN;                                       \
        *sP = hN; sP += Hc;                                                     \
        if ((T_) == Tc - 1) *hTp = hN;                                          \
        cr = nr; cz = nz; cxn = nx; hold = hN;                                  \
    }

    for (int t = 0; t < Tc; t += 2) {
        GRU_STEP(t, 0, xpre0);
        GRU_STEP(t + 1, 1, xpre1);
    }
#undef GRU_STEP
}

extern "C" void kernel_launch(void* const* d_in, const int* in_sizes, int n_in,
                              void* d_out, int out_size, void* d_ws, size_t ws_size,
                              hipStream_t stream) {
    const float* input = (const float*)d_in[0];
    const float* W_ih  = (const float*)d_in[1];
    const float* W_hh  = (const float*)d_in[2];
    const float* b_ih  = (const float*)d_in[3];
    const float* b_hh  = (const float*)d_in[4];
    float* out = (float*)d_out;
    (void)in_sizes; (void)n_in; (void)d_ws; (void)ws_size; (void)out_size;

    gru_mfma_kernel<<<NBLOCKS, 512, 0, stream>>>(input, W_ih, W_hh, b_ih, b_hh, out);
}